// Round 10
// baseline (271.109 us; speedup 1.0000x reference)
//
#include <hip/hip_runtime.h>
#include <math.h>

// Problem constants
#define D0 768
#define NH 12
#define DHD 64
#define NB 2
#define SQ 1024
#define SCX 256
#define ND 1025            // SQ + 1 (sos prepended)
#define NS 1281            // SCX + ND
#define TT (NB*ND)         // 2050 total h rows
#define TP 2176            // padded rows (34*64)
#define TC (NB*SCX)        // 512 context rows
#define KP 1344            // padded key rows for kU/vT (42*32)

typedef __attribute__((ext_vector_type(8))) short bf16x8;   // 8 bf16 in 4 VGPRs
typedef __attribute__((ext_vector_type(4))) float f32x4;

typedef const __attribute__((address_space(1))) unsigned int* gptr_t;
typedef __attribute__((address_space(3))) unsigned int* lptr_t;

__device__ __forceinline__ unsigned short f2bf(float f) {
    union { float f; unsigned u; } v; v.f = f;
    unsigned r = v.u + 0x7FFFu + ((v.u >> 16) & 1u);
    return (unsigned short)(r >> 16);
}

__device__ __forceinline__ float gelu_new(float x) {
    float x3 = x*x*x;
    float u = 0.7978845608028654f*(x + 0.044715f*x3);
    return 0.5f*x*(1.f + tanhf(u));
}

// ---------------- fused prep: build_h + ctx->bf16 + 5 weight transposes ----------------
struct PrepArgs {
    const float* x; const float* sos; float* h;
    const float* ctx; unsigned short* ctxb;
    const float* W[5]; unsigned short* Wt[5];
    int K[5], N[5], nblk[5];
};

#define NBH 1538           // ceil(TT*192/256)
#define NCVT 192           // TC*768/8/256

__global__ __launch_bounds__(256) void k_prep(PrepArgs a) {
    __shared__ float t[32][33];
    const int tid = threadIdx.x;
    int bid = blockIdx.x;
    if (bid < NBH) {                       // h = concat(sos, x)
        int idx = bid*256 + tid;
        if (idx < TT*192) {
            int r = idx/192, c4 = idx%192;
            int b = r/ND, tt = r%ND;
            float4 v;
            if (tt == 0) v = ((const float4*)a.sos)[c4];
            else         v = ((const float4*)a.x)[(size_t)(b*SQ + tt - 1)*192 + c4];
            ((float4*)a.h)[(size_t)r*192 + c4] = v;
        }
        return;
    }
    bid -= NBH;
    if (bid < NCVT) {                      // ctx f32 -> bf16
        int i = bid*256 + tid;
        float4 p = ((const float4*)a.ctx)[i*2];
        float4 q = ((const float4*)a.ctx)[i*2+1];
        uint4 o;
        o.x = (unsigned)f2bf(p.x) | ((unsigned)f2bf(p.y) << 16);
        o.y = (unsigned)f2bf(p.z) | ((unsigned)f2bf(p.w) << 16);
        o.z = (unsigned)f2bf(q.x) | ((unsigned)f2bf(q.y) << 16);
        o.w = (unsigned)f2bf(q.z) | ((unsigned)f2bf(q.w) << 16);
        ((uint4*)a.ctxb)[i] = o;
        return;
    }
    bid -= NCVT;
    #pragma unroll
    for (int wi = 0; wi < 5; ++wi) {
        if (bid < a.nblk[wi]) {            // W[K][N] f32 -> Wt[N][K] bf16
            const float* W = a.W[wi];
            unsigned short* Wt = a.Wt[wi];
            const int K = a.K[wi], N = a.N[wi];
            const int nbx = N >> 5;
            const int n0 = (bid % nbx)*32, k0 = (bid / nbx)*32;
            const int r = tid >> 3, c4 = (tid & 7)*4;
            float4 v = *(const float4*)&W[(size_t)(k0+r)*N + n0 + c4];
            t[r][c4+0]=v.x; t[r][c4+1]=v.y; t[r][c4+2]=v.z; t[r][c4+3]=v.w;
            __syncthreads();
            ushort4 o;
            o.x = f2bf(t[c4+0][r]); o.y = f2bf(t[c4+1][r]);
            o.z = f2bf(t[c4+2][r]); o.w = f2bf(t[c4+3][r]);
            *(ushort4*)&Wt[(size_t)(n0+r)*K + k0 + c4] = o;
            return;
        }
        bid -= a.nblk[wi];
    }
}

// LayerNorm over 768, bf16 output. Optional fused residual add (in += add -> resid).
__global__ __launch_bounds__(256) void k_ln(const float* __restrict__ in,
                                            const float* __restrict__ add,
                                            const float* __restrict__ g,
                                            const float* __restrict__ beta,
                                            unsigned short* __restrict__ out,
                                            float* __restrict__ resid,
                                            int nvalid) {
    int r = blockIdx.x;
    int tid = threadIdx.x;
    const size_t base = (size_t)r*D0;
    if (r >= nvalid) {
        out[base+tid] = 0; out[base+tid+256] = 0; out[base+tid+512] = 0;
        return;
    }
    float v0 = in[base+tid], v1 = in[base+tid+256], v2 = in[base+tid+512];
    if (add) {
        v0 += add[base+tid]; v1 += add[base+tid+256]; v2 += add[base+tid+512];
        resid[base+tid] = v0; resid[base+tid+256] = v1; resid[base+tid+512] = v2;
    }
    float s = v0+v1+v2;
    float ss = v0*v0 + v1*v1 + v2*v2;
    #pragma unroll
    for (int o = 32; o >= 1; o >>= 1) {
        s  += __shfl_down(s, o);
        ss += __shfl_down(ss, o);
    }
    __shared__ float red[8];
    __shared__ float mv[2];
    int w = tid >> 6;
    if ((tid & 63) == 0) { red[w] = s; red[4+w] = ss; }
    __syncthreads();
    if (tid == 0) {
        float S1 = red[0]+red[1]+red[2]+red[3];
        float S2 = red[4]+red[5]+red[6]+red[7];
        float mean = S1 * (1.f/D0);
        float var  = S2 * (1.f/D0) - mean*mean;
        mv[0] = mean; mv[1] = rsqrtf(var + 1e-5f);
    }
    __syncthreads();
    float mean = mv[0], rstd = mv[1];
    out[base+tid]     = f2bf((v0-mean)*rstd*g[tid]     + beta[tid]);
    out[base+tid+256] = f2bf((v1-mean)*rstd*g[tid+256] + beta[tid+256]);
    out[base+tid+512] = f2bf((v2-mean)*rstd*g[tid+512] + beta[tid+512]);
}

// bf16 MFMA GEMM body, 64x64 tile / BK=64: C = A[M,K] @ Bt[N,K]^T + bias.
// 4 waves 2x2, each 32x32 out (2x2 frags). LDS chunk-XOR swizzle by row&7 on
// BOTH global_load_lds source and ds_read (rule #21 involution).
template<int GELU, int OUTBF>
__device__ __forceinline__ void gemm64_body(unsigned short* As, unsigned short* Bs,
                                            const unsigned short* __restrict__ A,
                                            const unsigned short* __restrict__ Bt,
                                            const float* __restrict__ bias,
                                            void* __restrict__ Cv,
                                            int N, int K, int bx, int by) {
    const int tid = threadIdx.x;
    const int w = tid >> 6;
    const int l = tid & 63;
    const int wm = w >> 1, wn = w & 1;
    const int m0 = by * 64, n0 = bx * 64;

    f32x4 acc[2][2] = {};

    for (int k0 = 0; k0 < K; k0 += 64) {
        __syncthreads();
        #pragma unroll
        for (int i = 0; i < 2; ++i) {
            int s = i*256 + tid;             // 16B slot 0..511
            int row = s >> 3;
            int ch  = (s & 7) ^ (row & 7);   // logical k-chunk stored at this slot
            const unsigned short* ga = A  + (size_t)(m0 + row)*K + k0 + ch*8;
            const unsigned short* gb = Bt + (size_t)(n0 + row)*K + k0 + ch*8;
            lptr_t la = (lptr_t)(As + (i*256 + w*64)*8);   // wave-uniform base
            lptr_t lb = (lptr_t)(Bs + (i*256 + w*64)*8);
            __builtin_amdgcn_global_load_lds((gptr_t)ga, la, 16, 0, 0);
            __builtin_amdgcn_global_load_lds((gptr_t)gb, lb, 16, 0, 0);
        }
        __syncthreads();
        #pragma unroll
        for (int kc = 0; kc < 2; ++kc) {
            const int kchunk = kc*4 + (l >> 4);
            bf16x8 a[2], b[2];
            #pragma unroll
            for (int mi = 0; mi < 2; ++mi) {
                int row = wm*32 + mi*16 + (l & 15);
                a[mi] = *(const bf16x8*)&As[row*64 + ((kchunk ^ (row & 7))*8)];
            }
            #pragma unroll
            for (int ni = 0; ni < 2; ++ni) {
                int row = wn*32 + ni*16 + (l & 15);
                b[ni] = *(const bf16x8*)&Bs[row*64 + ((kchunk ^ (row & 7))*8)];
            }
            #pragma unroll
            for (int mi = 0; mi < 2; ++mi)
                #pragma unroll
                for (int ni = 0; ni < 2; ++ni)
                    acc[mi][ni] = __builtin_amdgcn_mfma_f32_16x16x32_bf16(a[mi], b[ni], acc[mi][ni], 0, 0, 0);
        }
    }

    // Epilogue. C/D layout (HW-verified): col = lane&15, row = (lane>>4)*4 + reg.
    float* Cf = (float*)Cv;
    unsigned short* Cb = (unsigned short*)Cv;
    const int rbase = m0 + wm*32 + (l >> 4)*4;
    const int cbase = n0 + wn*32 + (l & 15);
    #pragma unroll
    for (int ni = 0; ni < 2; ++ni) {
        int col = cbase + ni*16;
        float bv = bias[col];
        #pragma unroll
        for (int mi = 0; mi < 2; ++mi) {
            #pragma unroll
            for (int r = 0; r < 4; ++r) {
                int row = rbase + mi*16 + r;
                float v = acc[mi][ni][r] + bv;
                if (GELU) v = gelu_new(v);
                if (OUTBF) Cb[(size_t)row*N + col] = f2bf(v);
                else       Cf[(size_t)row*N + col] = v;
            }
        }
    }
}

template<int GELU, int OUTBF>
__global__ __launch_bounds__(256) void k_gemm64(const unsigned short* __restrict__ A,
                                                const unsigned short* __restrict__ Bt,
                                                const float* __restrict__ bias,
                                                void* __restrict__ Cv,
                                                int N, int K) {
    __shared__ unsigned short As[64*64];
    __shared__ unsigned short Bs[64*64];
    gemm64_body<GELU,OUTBF>(As, Bs, A, Bt, bias, Cv, N, K, blockIdx.x, blockIdx.y);
}

// Merged qkv (1224 blocks) + ckv (192 blocks) in one launch: fills CUs better.
__global__ __launch_bounds__(256) void k_gemm_qkvckv(const unsigned short* __restrict__ hlb,
                                                     const unsigned short* __restrict__ WatT,
                                                     const float* __restrict__ bat,
                                                     unsigned short* __restrict__ qkvb,
                                                     const unsigned short* __restrict__ ctxb,
                                                     const unsigned short* __restrict__ WrefT,
                                                     const float* __restrict__ bref,
                                                     unsigned short* __restrict__ ckvb) {
    __shared__ unsigned short As[64*64];
    __shared__ unsigned short Bs[64*64];
    int bid = blockIdx.x;
    if (bid < (2304/64)*(TP/64)) {
        gemm64_body<0,1>(As, Bs, hlb, WatT, bat, qkvb, 2304, 768, bid % (2304/64), bid / (2304/64));
    } else {
        bid -= (2304/64)*(TP/64);
        gemm64_body<0,1>(As, Bs, ctxb, WrefT, bref, ckvb, 1536, 768, bid % (1536/64), bid / (1536/64));
    }
}

// ---------------- K/V pack: kU[bh][KP][64] (unified K) + vT[bh][64][KP] (V^T) ----------------
// Grid (KP/32, 24), 256 thr. Zero-pads keys >= NS.
__global__ __launch_bounds__(256) void k_kvt(const unsigned short* __restrict__ qkvb,
                                             const unsigned short* __restrict__ ckvb,
                                             unsigned short* __restrict__ kU,
                                             unsigned short* __restrict__ vT) {
    const int bh = blockIdx.y;
    const int b = bh / NH, hh = bh % NH;
    const int key0 = blockIdx.x * 32;
    const int tid = threadIdx.x;
    __shared__ unsigned short tv[64][34];
    const int r = tid >> 3, c = tid & 7;     // key row r (0..31), 16B chunk c (0..7)
    const int kg = key0 + r;
    uint4 kvv = make_uint4(0,0,0,0), vvv = make_uint4(0,0,0,0);
    if (kg < NS) {
        const unsigned short* src = (kg < SCX)
            ? ckvb + (size_t)(b*SCX + kg)*1536 + hh*64 + c*8
            : qkvb + (size_t)(b*ND + kg - SCX)*2304 + 768 + hh*64 + c*8;
        kvv = *(const uint4*)src;
        vvv = *(const uint4*)(src + 768);
    }
    *(uint4*)(kU + ((size_t)bh*KP + key0 + r)*64 + c*8) = kvv;   // coalesced row write
    union { uint4 u; unsigned short s[8]; } vu; vu.u = vvv;
    #pragma unroll
    for (int j = 0; j < 8; ++j) tv[c*8 + j][r] = vu.s[j];
    __syncthreads();
    const int d = tid >> 2, kc = tid & 3;
    unsigned short o[8];
    #pragma unroll
    for (int j = 0; j < 8; ++j) o[j] = tv[d][kc*8 + j];
    *(uint4*)(vT + ((size_t)bh*64 + d)*KP + key0 + kc*8) = *(uint4*)o;
}

// ---------------- MFMA flash attention (direct-L2 fragments, barrier-free loop) ----------------
// Grid (33, 24), 256 thr. Wave = (q-subtile w>>1 of 16 rows) x (kv-half w&1).
// K frags from kU, V^T frags from vT -- straight from global (L2-resident),
// NO K/V LDS staging, NO loop barriers. P via 1KB/wave LDS (R9-verified swizzle).
// End: 2-partial flash-combine per q-subtile pair.
__global__ __launch_bounds__(256, 4) void k_attn_mfma(const unsigned short* __restrict__ qkvb,
                                                      const unsigned short* __restrict__ kU,
                                                      const unsigned short* __restrict__ vT,
                                                      unsigned short* __restrict__ attnob) {
    const int bh = blockIdx.y;
    const int b = bh / NH, hh = bh % NH;
    const int tid = threadIdx.x;
    const int w = tid >> 6;
    const int l = tid & 63;
    const int lg = l >> 4;       // 0..3
    const int ll = l & 15;
    const int kvh = w & 1;

    const int q0 = (32 - blockIdx.x)*32 + (w >> 1)*16;   // heavy q-tiles first

    __shared__ unsigned short Ps[4][512];   // per-wave P [16][32], granule-swizzled
    __shared__ float Om[4][16][68];         // combine: per-wave O partial (pad 68)
    __shared__ float Ml[4][16][2];          // combine: per-wave (m, l)

    const unsigned short* kB = kU + (size_t)bh*KP*64;
    const unsigned short* vB = vT + (size_t)bh*64*KP;
    unsigned short* Pw = Ps[w];

    // Q fragments: lane holds Q[q = q0+ll][kc*32 + lg*8 .. +8]
    bf16x8 qf[2];
    {
        int qc = min(q0 + ll, ND-1);
        const unsigned short* qrow = qkvb + (size_t)(b*ND + qc)*2304 + hh*64;
        qf[0] = *(const bf16x8*)(qrow + lg*8);
        qf[1] = *(const bf16x8*)(qrow + 32 + lg*8);
    }

    f32x4 o_acc[4] = {};
    float mrow[4], lrow[4];
    #pragma unroll
    for (int i = 0; i < 4; ++i) { mrow[i] = -1e30f; lrow[i] = 0.f; }

    const int nt = (q0 + 15 + SCX)/32 + 1;   // kv tiles of 32

    for (int kt = kvh; kt < nt; kt += 2) {
        const int kbase = kt*32;
        // ---- K fragments straight from kU (16B/lane, L2 hits)
        bf16x8 kf[2][2];
        #pragma unroll
        for (int c = 0; c < 2; ++c) {
            const unsigned short* krow = kB + (size_t)(kbase + c*16 + ll)*64;
            kf[c][0] = *(const bf16x8*)(krow + lg*8);
            kf[c][1] = *(const bf16x8*)(krow + 32 + lg*8);
        }
        // ---- V^T fragments straight from vT
        bf16x8 vf[4];
        #pragma unroll
        for (int dc = 0; dc < 4; ++dc)
            vf[dc] = *(const bf16x8*)(vB + (size_t)(dc*16 + ll)*KP + kbase + lg*8);

        // ---- S = Q K^T
        f32x4 s_acc[2];
        #pragma unroll
        for (int c = 0; c < 2; ++c) {
            f32x4 z = {0.f, 0.f, 0.f, 0.f};
            z = __builtin_amdgcn_mfma_f32_16x16x32_bf16(qf[0], kf[c][0], z, 0, 0, 0);
            s_acc[c] = __builtin_amdgcn_mfma_f32_16x16x32_bf16(qf[1], kf[c][1], z, 0, 0, 0);
        }

        // ---- mask (boundary + pad keys; covers key >= NS since q+SCX <= NS-1)
        if (kbase + 31 > q0 + SCX) {
            #pragma unroll
            for (int c = 0; c < 2; ++c) {
                int key = kbase + c*16 + ll;
                #pragma unroll
                for (int i = 0; i < 4; ++i) {
                    int q = q0 + lg*4 + i;
                    if (key > q + SCX) s_acc[c][i] = -1e30f;
                }
            }
        }

        // ---- online softmax (row = lg*4+i; reduce over 16 ll lanes)
        float tmax[4];
        #pragma unroll
        for (int i = 0; i < 4; ++i) {
            float tm = fmaxf(s_acc[0][i], s_acc[1][i]);
            #pragma unroll
            for (int o = 1; o < 16; o <<= 1) tm = fmaxf(tm, __shfl_xor(tm, o));
            tmax[i] = tm;
        }
        #pragma unroll
        for (int i = 0; i < 4; ++i) {
            float mnew = fmaxf(mrow[i], tmax[i]*0.125f);
            float fs = __expf(mrow[i] - mnew);
            mrow[i] = mnew;
            lrow[i] *= fs;
            #pragma unroll
            for (int dc = 0; dc < 4; ++dc) o_acc[dc][i] *= fs;
        }
        float psum[4] = {0.f, 0.f, 0.f, 0.f};
        #pragma unroll
        for (int c = 0; c < 2; ++c) {
            int kv = c*16 + ll;
            #pragma unroll
            for (int i = 0; i < 4; ++i) {
                float p = __expf(fmaf(s_acc[c][i], 0.125f, -mrow[i]));
                psum[i] += p;
                int q = lg*4 + i;          // local row 0..15; q>>2 == lg
                union { float f; unsigned u; } cv; cv.f = p;
                Pw[q*32 + (((kv>>3) ^ ((q>>2)&3))*8) + (kv&7)]
                    = (unsigned short)((cv.u + 0x8000u) >> 16);
            }
        }
        #pragma unroll
        for (int i = 0; i < 4; ++i) {
            float s = psum[i];
            #pragma unroll
            for (int o = 1; o < 16; o <<= 1) s += __shfl_xor(s, o);
            lrow[i] += s;
        }

        // ---- PV: O += P @ V^T  (kv=32 contraction -> 1 mfma per d-ctile)
        bf16x8 pf = *(const bf16x8*)(Pw + ll*32 + ((lg ^ ((ll>>2)&3))*8));
        #pragma unroll
        for (int dc = 0; dc < 4; ++dc)
            o_acc[dc] = __builtin_amdgcn_mfma_f32_16x16x32_bf16(pf, vf[dc], o_acc[dc], 0, 0, 0);
    }

    // ---- flash-combine the 2 kv-half partials per q-subtile pair
    __syncthreads();
    #pragma unroll
    for (int dc = 0; dc < 4; ++dc)
        #pragma unroll
        for (int i = 0; i < 4; ++i)
            Om[w][lg*4 + i][dc*16 + ll] = o_acc[dc][i];
    if (ll == 0) {
        #pragma unroll
        for (int i = 0; i < 4; ++i) {
            Ml[w][lg*4 + i][0] = mrow[i];
            Ml[w][lg*4 + i][1] = lrow[i];
        }
    }
    __syncthreads();
    const int pw = w ^ 1;
    #pragma unroll
    for (int i = 0; i < 4; ++i) {
        int row = lg*4 + i;
        float m0 = Ml[w][row][0],  l0 = Ml[w][row][1];
        float m1 = Ml[pw][row][0], l1 = Ml[pw][row][1];
        float M  = fmaxf(m0, m1);
        float e0 = __expf(m0 - M), e1 = __expf(m1 - M);
        float L  = l0*e0 + l1*e1;
        int q = q0 + row;
        if (q < ND) {
            unsigned short* orow = attnob + (size_t)(b*ND + q)*768 + hh*64;
            #pragma unroll
            for (int dc2 = 0; dc2 < 2; ++dc2) {
                int d = kvh*32 + dc2*16 + ll;    // pair waves write disjoint d halves
                float acc = e0*Om[w][row][d] + e1*Om[pw][row][d];
                orow[d] = f2bf(acc / L);
            }
        }
    }
}

// out[b,t,:] = h[b, t+1, :] + mproj[b, t+1, :]   (drop sos row)
__global__ void k_final(const float* __restrict__ h, const float* __restrict__ mp,
                        float* __restrict__ out) {
    int idx = blockIdx.x*blockDim.x + threadIdx.x;
    const int total = NB*SQ*192;
    if (idx >= total) return;
    int r = idx/192, c4 = idx%192;
    int b = r/SQ, t = r%SQ;
    size_t hr = (size_t)(b*ND + t + 1)*192 + c4;
    float4 hv = ((const float4*)h)[hr];
    float4 mv = ((const float4*)mp)[hr];
    ((float4*)out)[idx] = make_float4(hv.x+mv.x, hv.y+mv.y, hv.z+mv.z, hv.w+mv.w);
}

extern "C" void kernel_launch(void* const* d_in, const int* in_sizes, int n_in,
                              void* d_out, int out_size, void* d_ws, size_t ws_size,
                              hipStream_t stream) {
    const float* x     = (const float*)d_in[0];
    const float* ctx   = (const float*)d_in[1];
    const float* sos   = (const float*)d_in[2];
    const float* ln1g  = (const float*)d_in[3];
    const float* ln1b  = (const float*)d_in[4];
    const float* Wat   = (const float*)d_in[5];
    const float* bat   = (const float*)d_in[6];
    const float* Wref  = (const float*)d_in[7];
    const float* bref  = (const float*)d_in[8];
    const float* Wpj   = (const float*)d_in[9];
    const float* bpj   = (const float*)d_in[10];
    const float* ln2g  = (const float*)d_in[11];
    const float* ln2b  = (const float*)d_in[12];
    const float* Wfc   = (const float*)d_in[13];
    const float* bfc   = (const float*)d_in[14];
    const float* Wmp   = (const float*)d_in[15];
    const float* bmp   = (const float*)d_in[16];
    float* out = (float*)d_out;

    char* p = (char*)d_ws;
    float* h      = (float*)p;  p += (size_t)TP*768*4;
    float* aproj  = (float*)p;  p += (size_t)TP*768*4;
    unsigned short* qkvb   = (unsigned short*)p;  p += (size_t)TP*2304*2;
    unsigned short* ckvb   = (unsigned short*)p;  p += (size_t)TC*1536*2;
    unsigned short* hlb    = (unsigned short*)p;  p += (size_t)TP*768*2;
    unsigned short* attnob = (unsigned short*)p;  p += (size_t)TP*768*2;
    unsigned short* mfcb   = (unsigned short*)p;  p += (size_t)TP*3072*2;
    unsigned short* ctxb   = (unsigned short*)p;  p += (size_t)TC*768*2;
    unsigned short* kU     = (unsigned short*)p;  p += (size_t)NB*NH*KP*64*2;
    unsigned short* vT     = (unsigned short*)p;  p += (size_t)NB*NH*KP*64*2;
    unsigned short* WatT   = (unsigned short*)p;  p += (size_t)2304*768*2;
    unsigned short* WrefT  = (unsigned short*)p;  p += (size_t)1536*768*2;
    unsigned short* WpjT   = (unsigned short*)p;  p += (size_t)768*768*2;
    unsigned short* WfcT   = (unsigned short*)p;  p += (size_t)3072*768*2;
    unsigned short* WmpT   = (unsigned short*)p;  p += (size_t)768*3072*2;

    PrepArgs pa;
    pa.x = x; pa.sos = sos; pa.h = h; pa.ctx = ctx; pa.ctxb = ctxb;
    pa.W[0]=Wat;  pa.Wt[0]=WatT;  pa.K[0]=768;  pa.N[0]=2304; pa.nblk[0]=(2304/32)*(768/32);
    pa.W[1]=Wref; pa.Wt[1]=WrefT; pa.K[1]=768;  pa.N[1]=1536; pa.nblk[1]=(1536/32)*(768/32);
    pa.W[2]=Wpj;  pa.Wt[2]=WpjT;  pa.K[2]=768;  pa.N[2]=768;  pa.nblk[2]=(768/32)*(768/32);
    pa.W[3]=Wfc;  pa.Wt[3]=WfcT;  pa.K[3]=768;  pa.N[3]=3072; pa.nblk[3]=(3072/32)*(768/32);
    pa.W[4]=Wmp;  pa.Wt[4]=WmpT;  pa.K[4]=3072; pa.N[4]=768;  pa.nblk[4]=(768/32)*(3072/32);
    int nprep = NBH + NCVT + pa.nblk[0]+pa.nblk[1]+pa.nblk[2]+pa.nblk[3]+pa.nblk[4];

    k_prep<<<dim3(nprep), dim3(256), 0, stream>>>(pa);
    k_ln<<<dim3(TP), dim3(256), 0, stream>>>(h, nullptr, ln1g, ln1b, hlb, nullptr, TT);
    k_gemm_qkvckv<<<dim3((2304/64)*(TP/64) + (1536/64)*(TC/64)), dim3(256), 0, stream>>>(
        hlb, WatT, bat, qkvb, ctxb, WrefT, bref, ckvb);
    k_kvt<<<dim3(KP/32, NB*NH), dim3(256), 0, stream>>>(qkvb, ckvb, kU, vT);
    k_attn_mfma<<<dim3(33, NB*NH), dim3(256), 0, stream>>>(qkvb, kU, vT, attnob);
    k_gemm64<0,0><<<dim3(768/64, TP/64), dim3(256), 0, stream>>>(attnob, WpjT, bpj, aproj, 768, 768);
    k_ln<<<dim3(TP), dim3(256), 0, stream>>>(h, aproj, ln2g, ln2b, hlb, h, TT);
    k_gemm64<1,1><<<dim3(3072/64, TP/64), dim3(256), 0, stream>>>(hlb, WfcT, bfc, mfcb, 3072, 768);
    k_gemm64<0,0><<<dim3(768/64, TP/64), dim3(256), 0, stream>>>(mfcb, WmpT, bmp, aproj, 768, 3072);
    k_final<<<dim3((NB*SQ*192 + 255)/256), dim3(256), 0, stream>>>(h, aproj, out);
}

// Round 11
// 255.401 us; speedup vs baseline: 1.0615x; 1.0615x over previous
//
#include <hip/hip_runtime.h>
#include <math.h>

// Problem constants
#define D0 768
#define NH 12
#define DHD 64
#define NB 2
#define SQ 1024
#define SCX 256
#define ND 1025            // SQ + 1 (sos prepended)
#define NS 1281            // SCX + ND
#define TT (NB*ND)         // 2050 total h rows
#define TP 2176            // padded rows (34*64)
#define TC (NB*SCX)        // 512 context rows

typedef __attribute__((ext_vector_type(8))) short bf16x8;   // 8 bf16 in 4 VGPRs
typedef __attribute__((ext_vector_type(4))) float f32x4;

typedef const __attribute__((address_space(1))) unsigned int* gptr_t;
typedef __attribute__((address_space(3))) unsigned int* lptr_t;

__device__ __forceinline__ unsigned short f2bf(float f) {
    union { float f; unsigned u; } v; v.f = f;
    unsigned r = v.u + 0x7FFFu + ((v.u >> 16) & 1u);
    return (unsigned short)(r >> 16);
}

__device__ __forceinline__ float gelu_new(float x) {
    float x3 = x*x*x;
    float u = 0.7978845608028654f*(x + 0.044715f*x3);
    return 0.5f*x*(1.f + tanhf(u));
}

// ---------------- mega1: LN1(+h build) | ctx->bf16 | 5 weight transposes ----------------
struct Mega1Args {
    const float* x; const float* sos; float* h;
    const float* ctx; unsigned short* ctxb;
    const float* ln1g; const float* ln1b; unsigned short* hlb;
    const float* W[5]; unsigned short* Wt[5];
    int K[5], N[5], nblk[5];
};

#define NCVT 192           // TC*768/8/256

__global__ __launch_bounds__(256) void k_mega1(Mega1Args a) {
    __shared__ float t[32][33];
    __shared__ float red[8];
    __shared__ float mv[2];
    const int tid = threadIdx.x;
    int bid = blockIdx.x;
    if (bid < TP) {                         // LN1 row, building h from (sos|x)
        int r = bid;
        const size_t base = (size_t)r*D0;
        if (r >= TT) {
            a.hlb[base+tid] = 0; a.hlb[base+tid+256] = 0; a.hlb[base+tid+512] = 0;
            return;
        }
        int b = r/ND, tt = r%ND;
        const float* src = (tt == 0) ? a.sos : a.x + (size_t)(b*SQ + tt - 1)*D0;
        float v0 = src[tid], v1 = src[tid+256], v2 = src[tid+512];
        a.h[base+tid] = v0; a.h[base+tid+256] = v1; a.h[base+tid+512] = v2;
        float s = v0+v1+v2;
        float ss = v0*v0 + v1*v1 + v2*v2;
        #pragma unroll
        for (int o = 32; o >= 1; o >>= 1) {
            s  += __shfl_down(s, o);
            ss += __shfl_down(ss, o);
        }
        int w = tid >> 6;
        if ((tid & 63) == 0) { red[w] = s; red[4+w] = ss; }
        __syncthreads();
        if (tid == 0) {
            float S1 = red[0]+red[1]+red[2]+red[3];
            float S2 = red[4]+red[5]+red[6]+red[7];
            float mean = S1 * (1.f/D0);
            float var  = S2 * (1.f/D0) - mean*mean;
            mv[0] = mean; mv[1] = rsqrtf(var + 1e-5f);
        }
        __syncthreads();
        float mean = mv[0], rstd = mv[1];
        a.hlb[base+tid]     = f2bf((v0-mean)*rstd*a.ln1g[tid]     + a.ln1b[tid]);
        a.hlb[base+tid+256] = f2bf((v1-mean)*rstd*a.ln1g[tid+256] + a.ln1b[tid+256]);
        a.hlb[base+tid+512] = f2bf((v2-mean)*rstd*a.ln1g[tid+512] + a.ln1b[tid+512]);
        return;
    }
    bid -= TP;
    if (bid < NCVT) {                      // ctx f32 -> bf16
        int i = bid*256 + tid;
        float4 p = ((const float4*)a.ctx)[i*2];
        float4 q = ((const float4*)a.ctx)[i*2+1];
        uint4 o;
        o.x = (unsigned)f2bf(p.x) | ((unsigned)f2bf(p.y) << 16);
        o.y = (unsigned)f2bf(p.z) | ((unsigned)f2bf(p.w) << 16);
        o.z = (unsigned)f2bf(q.x) | ((unsigned)f2bf(q.y) << 16);
        o.w = (unsigned)f2bf(q.z) | ((unsigned)f2bf(q.w) << 16);
        ((uint4*)a.ctxb)[i] = o;
        return;
    }
    bid -= NCVT;
    #pragma unroll
    for (int wi = 0; wi < 5; ++wi) {
        if (bid < a.nblk[wi]) {            // W[K][N] f32 -> Wt[N][K] bf16
            const float* W = a.W[wi];
            unsigned short* Wt = a.Wt[wi];
            const int K = a.K[wi], N = a.N[wi];
            const int nbx = N >> 5;
            const int n0 = (bid % nbx)*32, k0 = (bid / nbx)*32;
            const int r = tid >> 3, c4 = (tid & 7)*4;
            float4 v = *(const float4*)&W[(size_t)(k0+r)*N + n0 + c4];
            t[r][c4+0]=v.x; t[r][c4+1]=v.y; t[r][c4+2]=v.z; t[r][c4+3]=v.w;
            __syncthreads();
            ushort4 o;
            o.x = f2bf(t[c4+0][r]); o.y = f2bf(t[c4+1][r]);
            o.z = f2bf(t[c4+2][r]); o.w = f2bf(t[c4+3][r]);
            *(ushort4*)&Wt[(size_t)(n0+r)*K + k0 + c4] = o;
            return;
        }
        bid -= a.nblk[wi];
    }
}

// LayerNorm over 768, bf16 output, fused residual add (in += add -> resid).
__global__ __launch_bounds__(256) void k_ln(const float* __restrict__ in,
                                            const float* __restrict__ add,
                                            const float* __restrict__ g,
                                            const float* __restrict__ beta,
                                            unsigned short* __restrict__ out,
                                            float* __restrict__ resid,
                                            int nvalid) {
    int r = blockIdx.x;
    int tid = threadIdx.x;
    const size_t base = (size_t)r*D0;
    if (r >= nvalid) {
        out[base+tid] = 0; out[base+tid+256] = 0; out[base+tid+512] = 0;
        return;
    }
    float v0 = in[base+tid], v1 = in[base+tid+256], v2 = in[base+tid+512];
    if (add) {
        v0 += add[base+tid]; v1 += add[base+tid+256]; v2 += add[base+tid+512];
        resid[base+tid] = v0; resid[base+tid+256] = v1; resid[base+tid+512] = v2;
    }
    float s = v0+v1+v2;
    float ss = v0*v0 + v1*v1 + v2*v2;
    #pragma unroll
    for (int o = 32; o >= 1; o >>= 1) {
        s  += __shfl_down(s, o);
        ss += __shfl_down(ss, o);
    }
    __shared__ float red[8];
    __shared__ float mv[2];
    int w = tid >> 6;
    if ((tid & 63) == 0) { red[w] = s; red[4+w] = ss; }
    __syncthreads();
    if (tid == 0) {
        float S1 = red[0]+red[1]+red[2]+red[3];
        float S2 = red[4]+red[5]+red[6]+red[7];
        float mean = S1 * (1.f/D0);
        float var  = S2 * (1.f/D0) - mean*mean;
        mv[0] = mean; mv[1] = rsqrtf(var + 1e-5f);
    }
    __syncthreads();
    float mean = mv[0], rstd = mv[1];
    out[base+tid]     = f2bf((v0-mean)*rstd*g[tid]     + beta[tid]);
    out[base+tid+256] = f2bf((v1-mean)*rstd*g[tid+256] + beta[tid+256]);
    out[base+tid+512] = f2bf((v2-mean)*rstd*g[tid+512] + beta[tid+512]);
}

// bf16 MFMA GEMM body, 64x64 tile / BK=64: C = A[M,K] @ Bt[N,K]^T + bias.
// 4 waves 2x2, each 32x32 out (2x2 frags). LDS chunk-XOR swizzle by row&7 on
// BOTH global_load_lds source and ds_read (rule #21 involution).
// FINAL=1: instead of writing C, writes fout[b*SQ+tt-1] = hres[row] + v
// (fused residual + sos-drop epilogue of the mproj GEMM).
template<int GELU, int OUTBF, int FINAL>
__device__ __forceinline__ void gemm64_body(unsigned short* As, unsigned short* Bs,
                                            const unsigned short* __restrict__ A,
                                            const unsigned short* __restrict__ Bt,
                                            const float* __restrict__ bias,
                                            void* __restrict__ Cv,
                                            const float* __restrict__ hres,
                                            float* __restrict__ fout,
                                            int N, int K, int bx, int by) {
    const int tid = threadIdx.x;
    const int w = tid >> 6;
    const int l = tid & 63;
    const int wm = w >> 1, wn = w & 1;
    const int m0 = by * 64, n0 = bx * 64;

    f32x4 acc[2][2] = {};

    for (int k0 = 0; k0 < K; k0 += 64) {
        __syncthreads();
        #pragma unroll
        for (int i = 0; i < 2; ++i) {
            int s = i*256 + tid;             // 16B slot 0..511
            int row = s >> 3;
            int ch  = (s & 7) ^ (row & 7);   // logical k-chunk stored at this slot
            const unsigned short* ga = A  + (size_t)(m0 + row)*K + k0 + ch*8;
            const unsigned short* gb = Bt + (size_t)(n0 + row)*K + k0 + ch*8;
            lptr_t la = (lptr_t)(As + (i*256 + w*64)*8);   // wave-uniform base
            lptr_t lb = (lptr_t)(Bs + (i*256 + w*64)*8);
            __builtin_amdgcn_global_load_lds((gptr_t)ga, la, 16, 0, 0);
            __builtin_amdgcn_global_load_lds((gptr_t)gb, lb, 16, 0, 0);
        }
        __syncthreads();
        #pragma unroll
        for (int kc = 0; kc < 2; ++kc) {
            const int kchunk = kc*4 + (l >> 4);
            bf16x8 a[2], b[2];
            #pragma unroll
            for (int mi = 0; mi < 2; ++mi) {
                int row = wm*32 + mi*16 + (l & 15);
                a[mi] = *(const bf16x8*)&As[row*64 + ((kchunk ^ (row & 7))*8)];
            }
            #pragma unroll
            for (int ni = 0; ni < 2; ++ni) {
                int row = wn*32 + ni*16 + (l & 15);
                b[ni] = *(const bf16x8*)&Bs[row*64 + ((kchunk ^ (row & 7))*8)];
            }
            #pragma unroll
            for (int mi = 0; mi < 2; ++mi)
                #pragma unroll
                for (int ni = 0; ni < 2; ++ni)
                    acc[mi][ni] = __builtin_amdgcn_mfma_f32_16x16x32_bf16(a[mi], b[ni], acc[mi][ni], 0, 0, 0);
        }
    }

    // Epilogue. C/D layout (HW-verified): col = lane&15, row = (lane>>4)*4 + reg.
    float* Cf = (float*)Cv;
    unsigned short* Cb = (unsigned short*)Cv;
    const int rbase = m0 + wm*32 + (l >> 4)*4;
    const int cbase = n0 + wn*32 + (l & 15);
    #pragma unroll
    for (int ni = 0; ni < 2; ++ni) {
        int col = cbase + ni*16;
        float bv = bias[col];
        #pragma unroll
        for (int mi = 0; mi < 2; ++mi) {
            #pragma unroll
            for (int r = 0; r < 4; ++r) {
                int row = rbase + mi*16 + r;
                float v = acc[mi][ni][r] + bv;
                if (FINAL) {
                    if (row < TT) {
                        int bb = row/ND, tt = row%ND;
                        if (tt >= 1)
                            fout[((size_t)bb*SQ + tt - 1)*D0 + col] = hres[(size_t)row*D0 + col] + v;
                    }
                } else {
                    if (GELU) v = gelu_new(v);
                    if (OUTBF) Cb[(size_t)row*N + col] = f2bf(v);
                    else       Cf[(size_t)row*N + col] = v;
                }
            }
        }
    }
}

template<int GELU, int OUTBF, int FINAL>
__global__ __launch_bounds__(256) void k_gemm64(const unsigned short* __restrict__ A,
                                                const unsigned short* __restrict__ Bt,
                                                const float* __restrict__ bias,
                                                void* __restrict__ Cv,
                                                const float* __restrict__ hres,
                                                float* __restrict__ fout,
                                                int N, int K) {
    __shared__ unsigned short As[64*64];
    __shared__ unsigned short Bs[64*64];
    gemm64_body<GELU,OUTBF,FINAL>(As, Bs, A, Bt, bias, Cv, hres, fout, N, K, blockIdx.x, blockIdx.y);
}

// Merged qkv (1224 blocks) + ckv (192 blocks) in one launch: fills CUs better.
__global__ __launch_bounds__(256) void k_gemm_qkvckv(const unsigned short* __restrict__ hlb,
                                                     const unsigned short* __restrict__ WatT,
                                                     const float* __restrict__ bat,
                                                     unsigned short* __restrict__ qkvb,
                                                     const unsigned short* __restrict__ ctxb,
                                                     const unsigned short* __restrict__ WrefT,
                                                     const float* __restrict__ bref,
                                                     unsigned short* __restrict__ ckvb) {
    __shared__ unsigned short As[64*64];
    __shared__ unsigned short Bs[64*64];
    int bid = blockIdx.x;
    if (bid < (2304/64)*(TP/64)) {
        gemm64_body<0,1,0>(As, Bs, hlb, WatT, bat, qkvb, nullptr, nullptr, 2304, 768, bid % (2304/64), bid / (2304/64));
    } else {
        bid -= (2304/64)*(TP/64);
        gemm64_body<0,1,0>(As, Bs, ctxb, WrefT, bref, ckvb, nullptr, nullptr, 1536, 768, bid % (1536/64), bid / (1536/64));
    }
}

// ---------------- MFMA flash attention (R7 structure -- best measured: 49 us) ----------------
// Block: 64 q rows x one (b,h); 4 waves, each one 16-row m-tile. Grid 17x24.
// q-tiles reversed so heavy (high-q0) blocks launch first.
__global__ __launch_bounds__(256, 2) void k_attn_mfma(const unsigned short* __restrict__ qkvb,
                                                      const unsigned short* __restrict__ ckvb,
                                                      unsigned short* __restrict__ attnob) {
    const int bh = blockIdx.y;
    const int b = bh / NH, hh = bh % NH;
    const int tid = threadIdx.x;
    const int w = tid >> 6;
    const int l = tid & 63;
    const int lg = l >> 4;       // 0..3
    const int ll = l & 15;

    const int q0 = (16 - blockIdx.x) * 64;   // reversed: heavy blocks first
    const int qw = q0 + w*16;

    __shared__ unsigned short Ks[64*64];      // [key][dh], chunk-swz by key&7
    __shared__ unsigned short Vt[64*64];      // [d][kv],  chunk-swz by d&7
    __shared__ unsigned short Ps[4][16*64];   // per-wave [q][kv], chunk-swz by q&7

    // Q fragments: lane holds Q[q=qw+ll][kc*32 + lg*8 .. +8]
    bf16x8 qf[2];
    {
        int qc = min(qw + ll, ND-1);
        const unsigned short* qrow = qkvb + (size_t)(b*ND + qc)*2304 + hh*64;
        qf[0] = *(const bf16x8*)(qrow + lg*8);
        qf[1] = *(const bf16x8*)(qrow + 32 + lg*8);
    }

    f32x4 o_acc[4] = {};
    float mrow[4], lrow[4];
    #pragma unroll
    for (int i = 0; i < 4; ++i) { mrow[i] = -1e30f; lrow[i] = 0.f; }

    const int qmax_blk = min(q0 + 63, ND-1);
    const int ntiles = (qmax_blk + SCX)/64 + 1;
    const int klim_wave = qw + 15 + SCX;

    for (int kt = 0; kt < ntiles; ++kt) {
        __syncthreads();   // previous tile's LDS reads done
        // ---- stage K via global_load_lds, pre-swizzled source
        #pragma unroll
        for (int it = 0; it < 2; ++it) {
            int slot = it*256 + tid;              // 16B slot 0..511
            int key  = slot >> 3;
            int ch   = (slot & 7) ^ (key & 7);
            int kg   = min(kt*64 + key, NS-1);
            const unsigned short* src;
            if (kg < SCX) src = ckvb + (size_t)(b*SCX + kg)*1536 + hh*64 + ch*8;
            else          src = qkvb + (size_t)(b*ND + kg - SCX)*2304 + 768 + hh*64 + ch*8;
            __builtin_amdgcn_global_load_lds((gptr_t)src, (lptr_t)(Ks + (size_t)(it*256 + w*64)*8), 16, 0, 0);
        }
        // ---- stage V transposed; lane map kv0=(tid&31)*2, dch=tid>>5 -> 2-way banks
        {
            int kv0 = (tid & 31)*2;
            int dch = tid >> 5;
            int kg0 = min(kt*64 + kv0,     NS-1);
            int kg1 = min(kt*64 + kv0 + 1, NS-1);
            const unsigned short* s0 = (kg0 < SCX)
                ? ckvb + (size_t)(b*SCX + kg0)*1536 + 768 + hh*64 + dch*8
                : qkvb + (size_t)(b*ND + kg0 - SCX)*2304 + 1536 + hh*64 + dch*8;
            const unsigned short* s1 = (kg1 < SCX)
                ? ckvb + (size_t)(b*SCX + kg1)*1536 + 768 + hh*64 + dch*8
                : qkvb + (size_t)(b*ND + kg1 - SCX)*2304 + 1536 + hh*64 + dch*8;
            union { uint4 u; unsigned short s[8]; } r0, r1;
            r0.u = *(const uint4*)s0;
            r1.u = *(const uint4*)s1;
            #pragma unroll
            for (int i = 0; i < 8; ++i) {
                int d = dch*8 + i;
                unsigned val = (unsigned)r0.s[i] | ((unsigned)r1.s[i] << 16);
                *(unsigned*)((char*)Vt + d*128 + (((kv0>>3) ^ (d&7))*16) + ((kv0&7)*2)) = val;
            }
        }
        __syncthreads();   // drains vmcnt (global_load_lds) + lgkm (ds writes)

        if (kt*64 > klim_wave) continue;   // wave-uniform: fully masked tile

        // ---- S = Q K^T
        bf16x8 kf[4][2];
        #pragma unroll
        for (int c = 0; c < 4; ++c) {
            int key = c*16 + ll;
            #pragma unroll
            for (int kc = 0; kc < 2; ++kc)
                kf[c][kc] = *(const bf16x8*)((char*)Ks + key*128 + (((kc*4 + lg) ^ (key&7))*16));
        }
        f32x4 s_acc[4];
        #pragma unroll
        for (int c = 0; c < 4; ++c) {
            f32x4 z = {0.f, 0.f, 0.f, 0.f};
            z = __builtin_amdgcn_mfma_f32_16x16x32_bf16(qf[0], kf[c][0], z, 0, 0, 0);
            s_acc[c] = __builtin_amdgcn_mfma_f32_16x16x32_bf16(qf[1], kf[c][1], z, 0, 0, 0);
        }

        // ---- mask (boundary tiles only)
        const int kbase = kt*64;
        if (kbase + 63 > qw + SCX) {
            #pragma unroll
            for (int c = 0; c < 4; ++c) {
                int key = kbase + c*16 + ll;
                #pragma unroll
                for (int i = 0; i < 4; ++i) {
                    int q = qw + lg*4 + i;
                    if (key > q + SCX) s_acc[c][i] = -1e30f;
                }
            }
        }

        // ---- online softmax (row r = lg*4+i; reduce over 16 ll lanes)
        float tmax[4];
        #pragma unroll
        for (int i = 0; i < 4; ++i) {
            float tm = fmaxf(fmaxf(s_acc[0][i], s_acc[1][i]),
                             fmaxf(s_acc[2][i], s_acc[3][i]));
            #pragma unroll
            for (int o = 1; o < 16; o <<= 1) tm = fmaxf(tm, __shfl_xor(tm, o));
            tmax[i] = tm;
        }
        #pragma unroll
        for (int i = 0; i < 4; ++i) {
            float mnew = fmaxf(mrow[i], tmax[i]*0.125f);
            float fs = __expf(mrow[i] - mnew);
            mrow[i] = mnew;
            lrow[i] *= fs;
            #pragma unroll
            for (int dc = 0; dc < 4; ++dc) o_acc[dc][i] *= fs;
        }
        float psum[4] = {0.f, 0.f, 0.f, 0.f};
        #pragma unroll
        for (int c = 0; c < 4; ++c) {
            int kv = c*16 + ll;
            #pragma unroll
            for (int i = 0; i < 4; ++i) {
                float p = __expf(fmaf(s_acc[c][i], 0.125f, -mrow[i]));
                psum[i] += p;
                int q = lg*4 + i;          // local row 0..15
                union { float f; unsigned u; } cv; cv.f = p;
                *(unsigned short*)((char*)Ps[w] + q*128 + (((kv>>3) ^ (q&7))*16) + ((kv&7)*2))
                    = (unsigned short)((cv.u + 0x8000u) >> 16);
            }
        }
        #pragma unroll
        for (int i = 0; i < 4; ++i) {
            float s = psum[i];
            #pragma unroll
            for (int o = 1; o < 16; o <<= 1) s += __shfl_xor(s, o);
            lrow[i] += s;
        }

        // ---- PV: O += P @ V  (A-frag from Ps, B-frag from Vt)
        #pragma unroll
        for (int kc = 0; kc < 2; ++kc) {
            int q = ll;
            bf16x8 pf = *(const bf16x8*)((char*)Ps[w] + q*128 + (((kc*4 + lg) ^ (q&7))*16));
            #pragma unroll
            for (int dc = 0; dc < 4; ++dc) {
                int d = dc*16 + ll;
                bf16x8 vf = *(const bf16x8*)((char*)Vt + d*128 + (((kc*4 + lg) ^ (d&7))*16));
                o_acc[dc] = __builtin_amdgcn_mfma_f32_16x16x32_bf16(pf, vf, o_acc[dc], 0, 0, 0);
            }
        }
    }

    // ---- epilogue: O / lsum -> bf16
    #pragma unroll
    for (int i = 0; i < 4; ++i) {
        int q = qw + lg*4 + i;
        if (q >= ND) continue;
        float inv = 1.f / lrow[i];
        unsigned short* orow = attnob + (size_t)(b*ND + q)*768 + hh*64;
        #pragma unroll
        for (int dc = 0; dc < 4; ++dc)
            orow[dc*16 + ll] = f2bf(o_acc[dc][i] * inv);
    }
}

extern "C" void kernel_launch(void* const* d_in, const int* in_sizes, int n_in,
                              void* d_out, int out_size, void* d_ws, size_t ws_size,
                              hipStream_t stream) {
    const float* x     = (const float*)d_in[0];
    const float* ctx   = (const float*)d_in[1];
    const float* sos   = (const float*)d_in[2];
    const float* ln1g  = (const float*)d_in[3];
    const float* ln1b  = (const float*)d_in[4];
    const float* Wat   = (const float*)d_in[5];
    const float* bat   = (const float*)d_in[6];
    const float* Wref  = (const float*)d_in[7];
    const float* bref  = (const float*)d_in[8];
    const float* Wpj   = (const float*)d_in[9];
    const float* bpj   = (const float*)d_in[10];
    const float* ln2g  = (const float*)d_in[11];
    const float* ln2b  = (const float*)d_in[12];
    const float* Wfc   = (const float*)d_in[13];
    const float* bfc   = (const float*)d_in[14];
    const float* Wmp   = (const float*)d_in[15];
    const float* bmp   = (const float*)d_in[16];
    float* out = (float*)d_out;

    char* p = (char*)d_ws;
    float* h      = (float*)p;  p += (size_t)TP*768*4;
    float* aproj  = (float*)p;  p += (size_t)TP*768*4;
    unsigned short* qkvb   = (unsigned short*)p;  p += (size_t)TP*2304*2;
    unsigned short* ckvb   = (unsigned short*)p;  p += (size_t)TC*1536*2;
    unsigned short* hlb    = (unsigned short*)p;  p += (size_t)TP*768*2;
    unsigned short* attnob = (unsigned short*)p;  p += (size_t)TP*768*2;
    unsigned short* mfcb   = (unsigned short*)p;  p += (size_t)TP*3072*2;
    unsigned short* ctxb   = (unsigned short*)p;  p += (size_t)TC*768*2;
    unsigned short* WatT   = (unsigned short*)p;  p += (size_t)2304*768*2;
    unsigned short* WrefT  = (unsigned short*)p;  p += (size_t)1536*768*2;
    unsigned short* WpjT   = (unsigned short*)p;  p += (size_t)768*768*2;
    unsigned short* WfcT   = (unsigned short*)p;  p += (size_t)3072*768*2;
    unsigned short* WmpT   = (unsigned short*)p;  p += (size_t)768*3072*2;

    Mega1Args ma;
    ma.x = x; ma.sos = sos; ma.h = h; ma.ctx = ctx; ma.ctxb = ctxb;
    ma.ln1g = ln1g; ma.ln1b = ln1b; ma.hlb = hlb;
    ma.W[0]=Wat;  ma.Wt[0]=WatT;  ma.K[0]=768;  ma.N[0]=2304; ma.nblk[0]=(2304/32)*(768/32);
    ma.W[1]=Wref; ma.Wt[1]=WrefT; ma.K[1]=768;  ma.N[1]=1536; ma.nblk[1]=(1536/32)*(768/32);
    ma.W[2]=Wpj;  ma.Wt[2]=WpjT;  ma.K[2]=768;  ma.N[2]=768;  ma.nblk[2]=(768/32)*(768/32);
    ma.W[3]=Wfc;  ma.Wt[3]=WfcT;  ma.K[3]=768;  ma.N[3]=3072; ma.nblk[3]=(3072/32)*(768/32);
    ma.W[4]=Wmp;  ma.Wt[4]=WmpT;  ma.K[4]=3072; ma.N[4]=768;  ma.nblk[4]=(768/32)*(3072/32);
    int nmega = TP + NCVT + ma.nblk[0]+ma.nblk[1]+ma.nblk[2]+ma.nblk[3]+ma.nblk[4];

    k_mega1<<<dim3(nmega), dim3(256), 0, stream>>>(ma);
    k_gemm_qkvckv<<<dim3((2304/64)*(TP/64) + (1536/64)*(TC/64)), dim3(256), 0, stream>>>(
        hlb, WatT, bat, qkvb, ctxb, WrefT, bref, ckvb);
    k_attn_mfma<<<dim3(17, NB*NH), dim3(256), 0, stream>>>(qkvb, ckvb, attnob);
    k_gemm64<0,0,0><<<dim3(768/64, TP/64), dim3(256), 0, stream>>>(attnob, WpjT, bpj, aproj, nullptr, nullptr, 768, 768);
    k_ln<<<dim3(TP), dim3(256), 0, stream>>>(h, aproj, ln2g, ln2b, hlb, h, TT);
    k_gemm64<1,1,0><<<dim3(3072/64, TP/64), dim3(256), 0, stream>>>(hlb, WfcT, bfc, mfcb, nullptr, nullptr, 3072, 768);
    k_gemm64<0,0,1><<<dim3(768/64, TP/64), dim3(256), 0, stream>>>(mfcb, WmpT, bmp, aproj, h, out, 768, 3072);
}